// Round 1
// baseline (8270.898 us; speedup 1.0000x reference)
//
#include <hip/hip_runtime.h>

typedef unsigned int uint32;
typedef unsigned short ushort16;
typedef __attribute__((ext_vector_type(8))) short short8;
typedef __attribute__((ext_vector_type(4))) float f32x4;

__device__ __forceinline__ float bf2f(ushort16 u) {
    return __uint_as_float(((uint32)u) << 16);
}
__device__ __forceinline__ ushort16 f2bf(float f) {
    uint32 u = __float_as_uint(f);
    return (ushort16)((u + 0x7FFFu + ((u >> 16) & 1u)) >> 16);  // RNE
}

// ---------------- f32 -> bf16 convert (vectorized x4) ----------------
__global__ __launch_bounds__(256) void k_cvt_bf16(const float* __restrict__ in,
                                                  ushort16* __restrict__ out, int n4) {
    int i = blockIdx.x * 256 + threadIdx.x;
    int stride = gridDim.x * 256;
    for (; i < n4; i += stride) {
        float4 v = ((const float4*)in)[i];
        ushort4 o;
        o.x = f2bf(v.x); o.y = f2bf(v.y); o.z = f2bf(v.z); o.w = f2bf(v.w);
        ((ushort4*)out)[i] = o;
    }
}

// ------- Whh [2][4H=1024][256] f32  ->  WhhT bf16 [d][kp=128][u=256][g=4][k2=2] -------
__global__ __launch_bounds__(256) void k_whhT(const float* __restrict__ whh,
                                              ushort16* __restrict__ out) {
    int i = blockIdx.x * 256 + threadIdx.x;   // 0 .. 524287
    int k2 = i & 1;
    int g  = (i >> 1) & 3;
    int u  = (i >> 3) & 255;
    int kp = (i >> 11) & 127;
    int d  = (i >> 18) & 1;
    int k = kp * 2 + k2;
    float v = whh[(size_t)((d * 4 + g) * 256 + u) * 256 + k];  // whh[d][g*256+u][k]
    out[i] = f2bf(v);
}

// ---------------- bf16 MFMA GEMM:  C[M,N] = A[M,K] * Bt[N,K]^T + bias[N] ----------------
// 128x128 tile, BK=32, 256 threads (4 waves, each 64x64), register-staged LDS.
__global__ __launch_bounds__(256) void k_gemm_bt(const ushort16* __restrict__ A,
                                                 const ushort16* __restrict__ Bt,
                                                 const float* __restrict__ bias,
                                                 ushort16* __restrict__ C,
                                                 int M, int N, int K) {
    __shared__ ushort16 As[128 * 32];   // [row][k] 8KB
    __shared__ ushort16 Bs[128 * 32];
    const int tid = threadIdx.x;
    const int bm = blockIdx.x * 128, bn = blockIdx.y * 128;
    const int lane = tid & 63, wave = tid >> 6;
    const int wr = (wave >> 1) * 64, wc = (wave & 1) * 64;
    const int l15 = lane & 15, l4 = lane >> 4;
    f32x4 acc[4][4] = {};
    const int ar = tid >> 2;            // staging row 0..63
    const int ac = (tid & 3) * 8;       // staging k-offset (x8 bf16 = 16B)
    const size_t rowA  = (size_t)(bm + ar) * K;
    const size_t rowA2 = (size_t)(bm + ar + 64) * K;
    const size_t rowB  = (size_t)(bn + ar) * K;
    const size_t rowB2 = (size_t)(bn + ar + 64) * K;

    for (int k0 = 0; k0 < K; k0 += 32) {
        uint4 a0 = *(const uint4*)&A[rowA + k0 + ac];
        uint4 a1 = *(const uint4*)&A[rowA2 + k0 + ac];
        uint4 b0 = *(const uint4*)&Bt[rowB + k0 + ac];
        uint4 b1 = *(const uint4*)&Bt[rowB2 + k0 + ac];
        *(uint4*)&As[tid * 8]        = a0;
        *(uint4*)&As[2048 + tid * 8] = a1;
        *(uint4*)&Bs[tid * 8]        = b0;
        *(uint4*)&Bs[2048 + tid * 8] = b1;
        __syncthreads();

        short8 af[4], bfv[4];
#pragma unroll
        for (int i = 0; i < 4; i++) {
            af[i]  = *(const short8*)&As[(wr + i * 16 + l15) * 32 + l4 * 8];
            bfv[i] = *(const short8*)&Bs[(wc + i * 16 + l15) * 32 + l4 * 8];
        }
#pragma unroll
        for (int mi = 0; mi < 4; mi++)
#pragma unroll
            for (int ni = 0; ni < 4; ni++)
                acc[mi][ni] = __builtin_amdgcn_mfma_f32_16x16x32_bf16(af[mi], bfv[ni],
                                                                     acc[mi][ni], 0, 0, 0);
        __syncthreads();
    }

#pragma unroll
    for (int mi = 0; mi < 4; mi++) {
#pragma unroll
        for (int ni = 0; ni < 4; ni++) {
            int col = bn + wc + ni * 16 + l15;
            float bv = bias[col];
#pragma unroll
            for (int r = 0; r < 4; r++) {
                int row = bm + wr + mi * 16 + l4 * 4 + r;
                C[(size_t)row * N + col] = f2bf(acc[mi][ni][r] + bv);
            }
        }
    }
}

// ---------------- LSTM scan: 1 block = (batch b, direction d); 256 threads = 256 h-units ----------------
// xg: [B*T][2048] bf16 (dir-major: d*1024 + gate*256 + u), WhhT per layout above,
// hout: [B*T][512] bf16 (d*256 + u)
__global__ __launch_bounds__(256) void k_lstm_scan(const ushort16* __restrict__ xg,
                                                   const ushort16* __restrict__ whhT,
                                                   ushort16* __restrict__ hout) {
    const int b = blockIdx.x >> 1, d = blockIdx.x & 1;
    const int u = threadIdx.x;
    __shared__ float hb[2][256];
    float c = 0.f;
    hb[0][u] = 0.f;
    __syncthreads();
    const uint4* __restrict__ wp = (const uint4*)(whhT + (size_t)d * 262144) + u;
    int cur = 0;
    for (int s = 0; s < 512; ++s) {
        int tt = d ? (511 - s) : s;
        const ushort16* xgp = xg + ((size_t)(b * 512 + tt)) * 2048 + d * 1024 + u;
        float p0 = bf2f(xgp[0]);
        float p1 = bf2f(xgp[256]);
        float p2 = bf2f(xgp[512]);
        float p3 = bf2f(xgp[768]);
        const float* hrow = hb[cur];
#pragma unroll 4
        for (int kp = 0; kp < 128; ++kp) {
            float hx = hrow[kp * 2], hy = hrow[kp * 2 + 1];
            uint4 wv = wp[kp * 256];
            p0 += __uint_as_float(wv.x << 16) * hx + __uint_as_float(wv.x & 0xffff0000u) * hy;
            p1 += __uint_as_float(wv.y << 16) * hx + __uint_as_float(wv.y & 0xffff0000u) * hy;
            p2 += __uint_as_float(wv.z << 16) * hx + __uint_as_float(wv.z & 0xffff0000u) * hy;
            p3 += __uint_as_float(wv.w << 16) * hx + __uint_as_float(wv.w & 0xffff0000u) * hy;
        }
        float ig = 1.f / (1.f + __expf(-p0));
        float fg = 1.f / (1.f + __expf(-p1));
        float gg = 1.f - 2.f / (__expf(2.f * p2) + 1.f);   // tanh
        float og = 1.f / (1.f + __expf(-p3));
        c = fg * c + ig * gg;
        float h = og * (1.f - 2.f / (__expf(2.f * c) + 1.f));
        hb[cur ^ 1][u] = h;
        hout[((size_t)(b * 512 + tt)) * 512 + d * 256 + u] = f2bf(h);
        cur ^= 1;
        __syncthreads();
    }
}

// ---------------- logits = h1[32768,512](bf16) @ clsW[9,512]^T + clsb -> f32 ----------------
__global__ __launch_bounds__(256) void k_logits(const ushort16* __restrict__ h1,
                                                const float* __restrict__ Wc,
                                                const float* __restrict__ bc,
                                                float* __restrict__ out) {
    __shared__ ushort16 hs[16 * 512];   // 16KB
    __shared__ float wsm[9 * 512];      // 18KB
    __shared__ float bs[9];
    const int tid = threadIdx.x;
    const size_t row0 = (size_t)blockIdx.x * 16;
    const uint4* src = (const uint4*)(h1 + row0 * 512);
    uint4* dst = (uint4*)hs;
#pragma unroll
    for (int i = 0; i < 4; i++) dst[tid + i * 256] = src[tid + i * 256];
    for (int i = tid; i < 4608; i += 256) wsm[i] = Wc[i];
    if (tid < 9) bs[tid] = bc[tid];
    __syncthreads();
    if (tid < 144) {
        int r = tid / 9, l = tid - r * 9;
        float acc = bs[l];
        const ushort16* hr = &hs[r * 512];
        const float* wrow = &wsm[l * 512];
        for (int k = 0; k < 512; k++) acc += bf2f(hr[k]) * wrow[k];
        out[(row0 + r) * 9 + l] = acc;
    }
}

// ---------------- CRF NLL per batch (timesteps [1, 511)) ----------------
__global__ __launch_bounds__(64) void k_crf(const float* __restrict__ logits,
                                            const int* __restrict__ labels,
                                            const float* __restrict__ start,
                                            const float* __restrict__ endv,
                                            const float* __restrict__ trans,
                                            float* __restrict__ perb) {
    const int b = blockIdx.x, lane = threadIdx.x;
    __shared__ float tr[81];
    __shared__ float emb[510 * 9];       // emissions t=1..510
    for (int i = lane; i < 81; i += 64) tr[i] = trans[i];
    const float* em = logits + (size_t)b * 512 * 9;
    for (int i = lane; i < 4590; i += 64) emb[i] = em[9 + i];
    __syncthreads();
    const int* lb = labels + (size_t)b * 512;

    // gold path score (emissions + transitions), wave-parallel
    float acc = 0.f;
    for (int s = lane; s < 510; s += 64) acc += emb[s * 9 + lb[s + 1]];
    for (int s = lane; s < 509; s += 64) acc += tr[lb[s + 1] * 9 + lb[s + 2]];
#pragma unroll
    for (int off = 32; off; off >>= 1) acc += __shfl_down(acc, off);

    // forward algorithm on lanes 0..8
    const int j = (lane < 9) ? lane : 0;
    float alpha = start[j] + emb[j];
    for (int s = 1; s < 510; ++s) {
        float v[9];
        float m = -3.4e38f;
#pragma unroll
        for (int i = 0; i < 9; i++) {
            float ai = __shfl(alpha, i);
            float t = ai + tr[i * 9 + j];
            v[i] = t;
            m = fmaxf(m, t);
        }
        float sum = 0.f;
#pragma unroll
        for (int i = 0; i < 9; i++) sum += __expf(v[i] - m);
        alpha = m + __logf(sum) + emb[s * 9 + j];
    }
    float ae = alpha + endv[j];
    float mm = -3.4e38f;
#pragma unroll
    for (int i = 0; i < 9; i++) mm = fmaxf(mm, __shfl(ae, i));
    float ss = 0.f;
#pragma unroll
    for (int i = 0; i < 9; i++) ss += __expf(__shfl(ae, i) - mm);
    float logZ = mm + __logf(ss);
    if (lane == 0) {
        float num = acc + start[lb[1]] + endv[lb[510]];
        perb[b] = logZ - num;
    }
}

__global__ __launch_bounds__(64) void k_reduce(const float* __restrict__ perb,
                                               float* __restrict__ out) {
    float v = perb[threadIdx.x];
#pragma unroll
    for (int off = 32; off; off >>= 1) v += __shfl_down(v, off);
    if (threadIdx.x == 0) out[0] = v * (1.f / 64.f);
}

extern "C" void kernel_launch(void* const* d_in, const int* in_sizes, int n_in,
                              void* d_out, int out_size, void* d_ws, size_t ws_size,
                              hipStream_t stream) {
    const float* features = (const float*)d_in[0];
    const int*   labels   = (const int*)d_in[1];
    const float* w0ih = (const float*)d_in[3];
    const float* w0hh = (const float*)d_in[4];
    const float* b0   = (const float*)d_in[5];
    const float* w1ih = (const float*)d_in[6];
    const float* w1hh = (const float*)d_in[7];
    const float* b1   = (const float*)d_in[8];
    const float* clsW = (const float*)d_in[9];
    const float* clsb = (const float*)d_in[10];
    const float* cstart = (const float*)d_in[11];
    const float* cend   = (const float*)d_in[12];
    const float* ctrans = (const float*)d_in[13];

    char* ws = (char*)d_ws;
    // layout (bytes): feat_bf 50331648 | xg 134217728 | h0 33554432 | wih0 3145728 |
    //                 wih1 2097152 | whhT0 1048576 | whhT1 1048576 | perb
    ushort16* featbf = (ushort16*)(ws + 0);
    ushort16* h1buf  = (ushort16*)(ws + 0);              // reuses feat region after layer0 GEMM
    ushort16* xg     = (ushort16*)(ws + 50331648);
    ushort16* h0     = (ushort16*)(ws + 184549376);
    ushort16* wih0   = (ushort16*)(ws + 218103808);
    ushort16* wih1   = (ushort16*)(ws + 221249536);
    ushort16* whhT0  = (ushort16*)(ws + 223346688);
    ushort16* whhT1  = (ushort16*)(ws + 224395264);
    float*    perb   = (float*)(ws + 225443840);

    float* outF = (float*)d_out;
    float* logitsF = outF + 1;

    k_cvt_bf16<<<dim3(2048), dim3(256), 0, stream>>>(features, featbf, 25165824 / 4);
    k_cvt_bf16<<<dim3(512), dim3(256), 0, stream>>>(w0ih, wih0, 1572864 / 4);
    k_cvt_bf16<<<dim3(512), dim3(256), 0, stream>>>(w1ih, wih1, 1048576 / 4);
    k_whhT<<<dim3(2048), dim3(256), 0, stream>>>(w0hh, whhT0);
    k_whhT<<<dim3(2048), dim3(256), 0, stream>>>(w1hh, whhT1);

    // layer 0
    k_gemm_bt<<<dim3(256, 16), dim3(256), 0, stream>>>(featbf, wih0, b0, xg, 32768, 2048, 768);
    k_lstm_scan<<<dim3(128), dim3(256), 0, stream>>>(xg, whhT0, h0);
    // layer 1
    k_gemm_bt<<<dim3(256, 16), dim3(256), 0, stream>>>(h0, wih1, b1, xg, 32768, 2048, 512);
    k_lstm_scan<<<dim3(128), dim3(256), 0, stream>>>(xg, whhT1, h1buf);
    // classifier + CRF
    k_logits<<<dim3(2048), dim3(256), 0, stream>>>(h1buf, clsW, clsb, logitsF);
    k_crf<<<dim3(64), dim3(64), 0, stream>>>(logitsF, labels, cstart, cend, ctrans, perb);
    k_reduce<<<dim3(1), dim3(64), 0, stream>>>(perb, outF);
}

// Round 2
// 5987.766 us; speedup vs baseline: 1.3813x; 1.3813x over previous
//
#include <hip/hip_runtime.h>

typedef unsigned int uint32;
typedef unsigned short ushort16;
typedef __attribute__((ext_vector_type(8))) short short8;
typedef __attribute__((ext_vector_type(4))) float f32x4;

__device__ __forceinline__ float bf2f(ushort16 u) {
    return __uint_as_float(((uint32)u) << 16);
}
__device__ __forceinline__ ushort16 f2bf(float f) {
    uint32 u = __float_as_uint(f);
    return (ushort16)((u + 0x7FFFu + ((u >> 16) & 1u)) >> 16);  // RNE
}

// ---------------- f32 -> bf16 convert (vectorized x4) ----------------
__global__ __launch_bounds__(256) void k_cvt_bf16(const float* __restrict__ in,
                                                  ushort16* __restrict__ out, int n4) {
    int i = blockIdx.x * 256 + threadIdx.x;
    int stride = gridDim.x * 256;
    for (; i < n4; i += stride) {
        float4 v = ((const float4*)in)[i];
        ushort4 o;
        o.x = f2bf(v.x); o.y = f2bf(v.y); o.z = f2bf(v.z); o.w = f2bf(v.w);
        ((ushort4*)out)[i] = o;
    }
}

// ------- Whh [2][4H=1024][256] f32 -> MFMA B-fragment order bf16 -------
// w2 flat index: ((((d*8 + w)*8 + nt)*8 + kf)*64 + lane)*8 + j
//   nt = g*2 + hh ; out_row = g*256 + w*32 + hh*16 + (lane&15)
//   k  = kf*32 + (lane>>4)*8 + j
__global__ __launch_bounds__(256) void k_wfrag(const float* __restrict__ whh,
                                               ushort16* __restrict__ out) {
    int i = blockIdx.x * 256 + threadIdx.x;   // 0 .. 524287
    int j    = i & 7;
    int lane = (i >> 3) & 63;
    int kf   = (i >> 9) & 7;
    int nt   = (i >> 12) & 7;
    int w    = (i >> 15) & 7;
    int d    = (i >> 18) & 1;
    int g = nt >> 1, hh = nt & 1;
    int orow = g * 256 + w * 32 + hh * 16 + (lane & 15);
    int k = kf * 32 + (lane >> 4) * 8 + j;
    float v = whh[((size_t)d * 1024 + orow) * 256 + k];
    out[i] = f2bf(v);
}

// ---------------- bf16 MFMA GEMM:  C[M,N] = A[M,K] * Bt[N,K]^T + bias[N] ----------------
__global__ __launch_bounds__(256) void k_gemm_bt(const ushort16* __restrict__ A,
                                                 const ushort16* __restrict__ Bt,
                                                 const float* __restrict__ bias,
                                                 ushort16* __restrict__ C,
                                                 int M, int N, int K) {
    __shared__ ushort16 As[128 * 32];
    __shared__ ushort16 Bs[128 * 32];
    const int tid = threadIdx.x;
    const int bm = blockIdx.x * 128, bn = blockIdx.y * 128;
    const int lane = tid & 63, wave = tid >> 6;
    const int wr = (wave >> 1) * 64, wc = (wave & 1) * 64;
    const int l15 = lane & 15, l4 = lane >> 4;
    f32x4 acc[4][4] = {};
    const int ar = tid >> 2;
    const int ac = (tid & 3) * 8;
    const size_t rowA  = (size_t)(bm + ar) * K;
    const size_t rowA2 = (size_t)(bm + ar + 64) * K;
    const size_t rowB  = (size_t)(bn + ar) * K;
    const size_t rowB2 = (size_t)(bn + ar + 64) * K;

    for (int k0 = 0; k0 < K; k0 += 32) {
        uint4 a0 = *(const uint4*)&A[rowA + k0 + ac];
        uint4 a1 = *(const uint4*)&A[rowA2 + k0 + ac];
        uint4 b0 = *(const uint4*)&Bt[rowB + k0 + ac];
        uint4 b1 = *(const uint4*)&Bt[rowB2 + k0 + ac];
        *(uint4*)&As[tid * 8]        = a0;
        *(uint4*)&As[2048 + tid * 8] = a1;
        *(uint4*)&Bs[tid * 8]        = b0;
        *(uint4*)&Bs[2048 + tid * 8] = b1;
        __syncthreads();

        short8 af[4], bfv[4];
#pragma unroll
        for (int i = 0; i < 4; i++) {
            af[i]  = *(const short8*)&As[(wr + i * 16 + l15) * 32 + l4 * 8];
            bfv[i] = *(const short8*)&Bs[(wc + i * 16 + l15) * 32 + l4 * 8];
        }
#pragma unroll
        for (int mi = 0; mi < 4; mi++)
#pragma unroll
            for (int ni = 0; ni < 4; ni++)
                acc[mi][ni] = __builtin_amdgcn_mfma_f32_16x16x32_bf16(af[mi], bfv[ni],
                                                                     acc[mi][ni], 0, 0, 0);
        __syncthreads();
    }

#pragma unroll
    for (int mi = 0; mi < 4; mi++) {
#pragma unroll
        for (int ni = 0; ni < 4; ni++) {
            int col = bn + wc + ni * 16 + l15;
            float bv = bias[col];
#pragma unroll
            for (int r = 0; r < 4; r++) {
                int row = bm + wr + mi * 16 + l4 * 4 + r;
                C[(size_t)row * N + col] = f2bf(acc[mi][ni][r] + bv);
            }
        }
    }
}

// ---------------- MFMA LSTM scan ----------------
// 8 blocks = 4 batch-groups(16) x 2 dirs; 512 threads = 8 waves; wave w owns h-units [32w,32w+32)
// (all 4 gates). Whh fragments: kf 0..4 in VGPRs, kf 5..6 in LDS, kf 7 streamed from L2.
// dynamic smem: hfrag[2][4096 bf16] (A-fragment order) @0, wlds 128KB @16384.
__global__ __launch_bounds__(512) void k_lstm_scan_mfma(const ushort16* __restrict__ xg,
                                                        const ushort16* __restrict__ w2,
                                                        ushort16* __restrict__ hout) {
    extern __shared__ char smem[];
    ushort16* hf = (ushort16*)smem;                 // 2 buffers x 4096 bf16
    ushort16* wl = (ushort16*)(smem + 16384);       // 65536 bf16

    const int bg = blockIdx.x >> 1, d = blockIdx.x & 1;
    const int tid = threadIdx.x;
    const int wv = tid >> 6, lane = tid & 63;
    const int l15 = lane & 15, l4 = lane >> 4;
    const size_t dbase = (size_t)d * 262144;

    // zero h buffers
    for (int q = tid; q < 1024; q += 512) ((uint4*)hf)[q] = make_uint4(0, 0, 0, 0);
    // prefill LDS weights (kf 5,6 for all waves): 8192 uint4
    {
        const uint4* src = (const uint4*)(w2 + dbase);
        uint4* dst = (uint4*)wl;
        for (int q = tid; q < 8192; q += 512) {
            int s = q >> 7;              // w*8+nt
            int kp = (q >> 6) & 1;
            int off = q & 63;
            dst[q] = src[(s * 8 + 5 + kp) * 64 + off];
        }
    }
    // register weights kf 0..4
    const ushort16* wbase = w2 + dbase + (size_t)wv * 32768 + lane * 8;
    short8 wreg[8][5];
#pragma unroll
    for (int nt = 0; nt < 8; ++nt)
#pragma unroll
        for (int kf = 0; kf < 5; ++kf)
            wreg[nt][kf] = *(const short8*)&wbase[nt * 4096 + kf * 512];
    const ushort16* w7 = wbase + 7 * 512;
    __syncthreads();

    float cst[2][4] = {{0.f, 0.f, 0.f, 0.f}, {0.f, 0.f, 0.f, 0.f}};
    int cur = 0;
    const ushort16* xgb = xg + (size_t)(bg * 16) * 1048576 + d * 1024 + wv * 32 + l15;

    for (int s = 0; s < 512; ++s) {
        const int tt = d ? (511 - s) : s;
        f32x4 acc[8] = {};
        const ushort16* hcur = hf + cur * 4096;

        // kf 0..4 from registers
#pragma unroll
        for (int kf = 0; kf < 5; ++kf) {
            short8 a = *(const short8*)&hcur[kf * 512 + lane * 8];
#pragma unroll
            for (int nt = 0; nt < 8; ++nt)
                acc[nt] = __builtin_amdgcn_mfma_f32_16x16x32_bf16(a, wreg[nt][kf], acc[nt], 0, 0, 0);
        }

        // xg loads (off critical path; consumed in epilogue)
        ushort16 xs[8][4];
        {
            const ushort16* xrow = xgb + (size_t)tt * 2048;
#pragma unroll
            for (int nt = 0; nt < 8; ++nt) {
                const int goff = (nt >> 1) * 256 + (nt & 1) * 16;
#pragma unroll
                for (int r = 0; r < 4; ++r)
                    xs[nt][r] = xrow[(size_t)(l4 * 4 + r) * 1048576 + goff];
            }
        }
        // stream kf7 (opaque offset defeats loop-invariant hoisting)
        int off7 = 0;
        asm volatile("" : "+v"(off7));
        short8 w7r[8];
#pragma unroll
        for (int nt = 0; nt < 8; ++nt) w7r[nt] = *(const short8*)&w7[nt * 4096 + off7];

        // kf 5,6 from LDS
#pragma unroll
        for (int kp = 0; kp < 2; ++kp) {
            short8 a = *(const short8*)&hcur[(5 + kp) * 512 + lane * 8];
#pragma unroll
            for (int nt = 0; nt < 8; ++nt) {
                short8 b = *(const short8*)&wl[((wv * 8 + nt) * 2 + kp) * 512 + lane * 8];
                acc[nt] = __builtin_amdgcn_mfma_f32_16x16x32_bf16(a, b, acc[nt], 0, 0, 0);
            }
        }
        // kf 7 streamed
        {
            short8 a = *(const short8*)&hcur[7 * 512 + lane * 8];
#pragma unroll
            for (int nt = 0; nt < 8; ++nt)
                acc[nt] = __builtin_amdgcn_mfma_f32_16x16x32_bf16(a, w7r[nt], acc[nt], 0, 0, 0);
        }

        // epilogue: gates -> c,h ; write h to next A-fragment buffer + global
        ushort16* hnxt = hf + (cur ^ 1) * 4096;
#pragma unroll
        for (int hh = 0; hh < 2; ++hh) {
#pragma unroll
            for (int r = 0; r < 4; ++r) {
                float ip = acc[0 + hh][r] + bf2f(xs[0 + hh][r]);
                float fp = acc[2 + hh][r] + bf2f(xs[2 + hh][r]);
                float gp = acc[4 + hh][r] + bf2f(xs[4 + hh][r]);
                float op = acc[6 + hh][r] + bf2f(xs[6 + hh][r]);
                float ig = 1.f / (1.f + __expf(-ip));
                float fg = 1.f / (1.f + __expf(-fp));
                float gg = 1.f - 2.f / (__expf(2.f * gp) + 1.f);
                float og = 1.f / (1.f + __expf(-op));
                float c = fg * cst[hh][r] + ig * gg;
                cst[hh][r] = c;
                float h = og * (1.f - 2.f / (__expf(2.f * c) + 1.f));
                ushort16 hb = f2bf(h);
                int u = wv * 32 + hh * 16 + l15;
                int row = l4 * 4 + r;
                hnxt[wv * 512 + ((hh * 2 + (l15 >> 3)) * 16 + row) * 8 + (l15 & 7)] = hb;
                hout[((size_t)(bg * 16 + row) * 512 + tt) * 512 + d * 256 + u] = hb;
            }
        }
        __syncthreads();
        cur ^= 1;
    }
}

// ---------------- logits = h1[32768,512](bf16) @ clsW[9,512]^T + clsb -> f32 ----------------
__global__ __launch_bounds__(256) void k_logits(const ushort16* __restrict__ h1,
                                                const float* __restrict__ Wc,
                                                const float* __restrict__ bc,
                                                float* __restrict__ out) {
    __shared__ ushort16 hs[16 * 512];
    __shared__ float wsm[9 * 512];
    __shared__ float bs[9];
    const int tid = threadIdx.x;
    const size_t row0 = (size_t)blockIdx.x * 16;
    const uint4* src = (const uint4*)(h1 + row0 * 512);
    uint4* dst = (uint4*)hs;
#pragma unroll
    for (int i = 0; i < 4; i++) dst[tid + i * 256] = src[tid + i * 256];
    for (int i = tid; i < 4608; i += 256) wsm[i] = Wc[i];
    if (tid < 9) bs[tid] = bc[tid];
    __syncthreads();
    if (tid < 144) {
        int r = tid / 9, l = tid - r * 9;
        float acc = bs[l];
        const ushort16* hr = &hs[r * 512];
        const float* wrow = &wsm[l * 512];
        for (int k = 0; k < 512; k++) acc += bf2f(hr[k]) * wrow[k];
        out[(row0 + r) * 9 + l] = acc;
    }
}

// ---------------- CRF NLL per batch (timesteps [1, 511)) ----------------
__global__ __launch_bounds__(64) void k_crf(const float* __restrict__ logits,
                                            const int* __restrict__ labels,
                                            const float* __restrict__ start,
                                            const float* __restrict__ endv,
                                            const float* __restrict__ trans,
                                            float* __restrict__ perb) {
    const int b = blockIdx.x, lane = threadIdx.x;
    __shared__ float tr[81];
    __shared__ float emb[510 * 9];
    for (int i = lane; i < 81; i += 64) tr[i] = trans[i];
    const float* em = logits + (size_t)b * 512 * 9;
    for (int i = lane; i < 4590; i += 64) emb[i] = em[9 + i];
    __syncthreads();
    const int* lb = labels + (size_t)b * 512;

    float acc = 0.f;
    for (int s = lane; s < 510; s += 64) acc += emb[s * 9 + lb[s + 1]];
    for (int s = lane; s < 509; s += 64) acc += tr[lb[s + 1] * 9 + lb[s + 2]];
#pragma unroll
    for (int off = 32; off; off >>= 1) acc += __shfl_down(acc, off);

    const int j = (lane < 9) ? lane : 0;
    float alpha = start[j] + emb[j];
    for (int s = 1; s < 510; ++s) {
        float v[9];
        float m = -3.4e38f;
#pragma unroll
        for (int i = 0; i < 9; i++) {
            float ai = __shfl(alpha, i);
            float t = ai + tr[i * 9 + j];
            v[i] = t;
            m = fmaxf(m, t);
        }
        float sum = 0.f;
#pragma unroll
        for (int i = 0; i < 9; i++) sum += __expf(v[i] - m);
        alpha = m + __logf(sum) + emb[s * 9 + j];
    }
    float ae = alpha + endv[j];
    float mm = -3.4e38f;
#pragma unroll
    for (int i = 0; i < 9; i++) mm = fmaxf(mm, __shfl(ae, i));
    float ss = 0.f;
#pragma unroll
    for (int i = 0; i < 9; i++) ss += __expf(__shfl(ae, i) - mm);
    float logZ = mm + __logf(ss);
    if (lane == 0) {
        float num = acc + start[lb[1]] + endv[lb[510]];
        perb[b] = logZ - num;
    }
}

__global__ __launch_bounds__(64) void k_reduce(const float* __restrict__ perb,
                                               float* __restrict__ out) {
    float v = perb[threadIdx.x];
#pragma unroll
    for (int off = 32; off; off >>= 1) v += __shfl_down(v, off);
    if (threadIdx.x == 0) out[0] = v * (1.f / 64.f);
}

extern "C" void kernel_launch(void* const* d_in, const int* in_sizes, int n_in,
                              void* d_out, int out_size, void* d_ws, size_t ws_size,
                              hipStream_t stream) {
    const float* features = (const float*)d_in[0];
    const int*   labels   = (const int*)d_in[1];
    const float* w0ih = (const float*)d_in[3];
    const float* w0hh = (const float*)d_in[4];
    const float* b0   = (const float*)d_in[5];
    const float* w1ih = (const float*)d_in[6];
    const float* w1hh = (const float*)d_in[7];
    const float* b1   = (const float*)d_in[8];
    const float* clsW = (const float*)d_in[9];
    const float* clsb = (const float*)d_in[10];
    const float* cstart = (const float*)d_in[11];
    const float* cend   = (const float*)d_in[12];
    const float* ctrans = (const float*)d_in[13];

    char* ws = (char*)d_ws;
    ushort16* featbf = (ushort16*)(ws + 0);
    ushort16* h1buf  = (ushort16*)(ws + 0);
    ushort16* xg     = (ushort16*)(ws + 50331648);
    ushort16* h0     = (ushort16*)(ws + 184549376);
    ushort16* wih0   = (ushort16*)(ws + 218103808);
    ushort16* wih1   = (ushort16*)(ws + 221249536);
    ushort16* w2_0   = (ushort16*)(ws + 223346688);
    ushort16* w2_1   = (ushort16*)(ws + 224395264);
    float*    perb   = (float*)(ws + 225443840);

    float* outF = (float*)d_out;
    float* logitsF = outF + 1;

    k_cvt_bf16<<<dim3(2048), dim3(256), 0, stream>>>(features, featbf, 25165824 / 4);
    k_cvt_bf16<<<dim3(512), dim3(256), 0, stream>>>(w0ih, wih0, 1572864 / 4);
    k_cvt_bf16<<<dim3(512), dim3(256), 0, stream>>>(w1ih, wih1, 1048576 / 4);
    k_wfrag<<<dim3(2048), dim3(256), 0, stream>>>(w0hh, w2_0);
    k_wfrag<<<dim3(2048), dim3(256), 0, stream>>>(w1hh, w2_1);

    // layer 0
    k_gemm_bt<<<dim3(256, 16), dim3(256), 0, stream>>>(featbf, wih0, b0, xg, 32768, 2048, 768);
    k_lstm_scan_mfma<<<dim3(8), dim3(512), 147456, stream>>>(xg, w2_0, h0);
    // layer 1
    k_gemm_bt<<<dim3(256, 16), dim3(256), 0, stream>>>(h0, wih1, b1, xg, 32768, 2048, 512);
    k_lstm_scan_mfma<<<dim3(8), dim3(512), 147456, stream>>>(xg, w2_1, h1buf);
    // classifier + CRF
    k_logits<<<dim3(2048), dim3(256), 0, stream>>>(h1buf, clsW, clsb, logitsF);
    k_crf<<<dim3(64), dim3(64), 0, stream>>>(logitsF, labels, cstart, cend, ctrans, perb);
    k_reduce<<<dim3(1), dim3(64), 0, stream>>>(perb, outF);
}

// Round 3
// 5725.021 us; speedup vs baseline: 1.4447x; 1.0459x over previous
//
#include <hip/hip_runtime.h>

typedef unsigned int uint32;
typedef unsigned short ushort16;
typedef __attribute__((ext_vector_type(8))) short short8;
typedef __attribute__((ext_vector_type(4))) float f32x4;

__device__ __forceinline__ float bf2f(ushort16 u) {
    return __uint_as_float(((uint32)u) << 16);
}
__device__ __forceinline__ ushort16 f2bf(float f) {
    uint32 u = __float_as_uint(f);
    return (ushort16)((u + 0x7FFFu + ((u >> 16) & 1u)) >> 16);  // RNE
}

// ---------------- f32 -> bf16 convert (vectorized x4) ----------------
__global__ __launch_bounds__(256) void k_cvt_bf16(const float* __restrict__ in,
                                                  ushort16* __restrict__ out, int n4) {
    int i = blockIdx.x * 256 + threadIdx.x;
    int stride = gridDim.x * 256;
    for (; i < n4; i += stride) {
        float4 v = ((const float4*)in)[i];
        ushort4 o;
        o.x = f2bf(v.x); o.y = f2bf(v.y); o.z = f2bf(v.z); o.w = f2bf(v.w);
        ((ushort4*)out)[i] = o;
    }
}

// ------- Whh [2][4H=1024][256] f32 -> MFMA B-fragment order bf16 -------
// w2 flat index: ((((d*8 + w)*8 + nt)*8 + kf)*64 + lane)*8 + j
//   nt = g*2 + hh ; out_row = g*256 + w*32 + hh*16 + (lane&15)
//   k  = kf*32 + (lane>>4)*8 + j
__global__ __launch_bounds__(256) void k_wfrag(const float* __restrict__ whh,
                                               ushort16* __restrict__ out) {
    int i = blockIdx.x * 256 + threadIdx.x;   // 0 .. 524287
    int j    = i & 7;
    int lane = (i >> 3) & 63;
    int kf   = (i >> 9) & 7;
    int nt   = (i >> 12) & 7;
    int w    = (i >> 15) & 7;
    int d    = (i >> 18) & 1;
    int g = nt >> 1, hh = nt & 1;
    int orow = g * 256 + w * 32 + hh * 16 + (lane & 15);
    int k = kf * 32 + (lane >> 4) * 8 + j;
    float v = whh[((size_t)d * 1024 + orow) * 256 + k];
    out[i] = f2bf(v);
}

// ---------------- bf16 MFMA GEMM:  C[M,N] = A[M,K] * Bt[N,K]^T + bias[N] ----------------
__global__ __launch_bounds__(256) void k_gemm_bt(const ushort16* __restrict__ A,
                                                 const ushort16* __restrict__ Bt,
                                                 const float* __restrict__ bias,
                                                 ushort16* __restrict__ C,
                                                 int M, int N, int K) {
    __shared__ ushort16 As[128 * 32];
    __shared__ ushort16 Bs[128 * 32];
    const int tid = threadIdx.x;
    const int bm = blockIdx.x * 128, bn = blockIdx.y * 128;
    const int lane = tid & 63, wave = tid >> 6;
    const int wr = (wave >> 1) * 64, wc = (wave & 1) * 64;
    const int l15 = lane & 15, l4 = lane >> 4;
    f32x4 acc[4][4] = {};
    const int ar = tid >> 2;
    const int ac = (tid & 3) * 8;
    const size_t rowA  = (size_t)(bm + ar) * K;
    const size_t rowA2 = (size_t)(bm + ar + 64) * K;
    const size_t rowB  = (size_t)(bn + ar) * K;
    const size_t rowB2 = (size_t)(bn + ar + 64) * K;

    for (int k0 = 0; k0 < K; k0 += 32) {
        uint4 a0 = *(const uint4*)&A[rowA + k0 + ac];
        uint4 a1 = *(const uint4*)&A[rowA2 + k0 + ac];
        uint4 b0 = *(const uint4*)&Bt[rowB + k0 + ac];
        uint4 b1 = *(const uint4*)&Bt[rowB2 + k0 + ac];
        *(uint4*)&As[tid * 8]        = a0;
        *(uint4*)&As[2048 + tid * 8] = a1;
        *(uint4*)&Bs[tid * 8]        = b0;
        *(uint4*)&Bs[2048 + tid * 8] = b1;
        __syncthreads();

        short8 af[4], bfv[4];
#pragma unroll
        for (int i = 0; i < 4; i++) {
            af[i]  = *(const short8*)&As[(wr + i * 16 + l15) * 32 + l4 * 8];
            bfv[i] = *(const short8*)&Bs[(wc + i * 16 + l15) * 32 + l4 * 8];
        }
#pragma unroll
        for (int mi = 0; mi < 4; mi++)
#pragma unroll
            for (int ni = 0; ni < 4; ni++)
                acc[mi][ni] = __builtin_amdgcn_mfma_f32_16x16x32_bf16(af[mi], bfv[ni],
                                                                     acc[mi][ni], 0, 0, 0);
        __syncthreads();
    }

#pragma unroll
    for (int mi = 0; mi < 4; mi++) {
#pragma unroll
        for (int ni = 0; ni < 4; ni++) {
            int col = bn + wc + ni * 16 + l15;
            float bv = bias[col];
#pragma unroll
            for (int r = 0; r < 4; r++) {
                int row = bm + wr + mi * 16 + l4 * 4 + r;
                C[(size_t)row * N + col] = f2bf(acc[mi][ni][r] + bv);
            }
        }
    }
}

// ---------------- MFMA LSTM scan ----------------
// 8 blocks = 4 batch-groups(16) x 2 dirs; 512 threads = 8 waves; wave w owns h-units [32w,32w+32)
// (all 4 gates). Whh fragments: kf 0..3 in VGPRs, kf 4..5 in LDS, kf 6,7 streamed from L2.
// dynamic smem: hfrag[2][4096 bf16] (A-fragment order, XOR-swizzled chunks) @0, wlds 128KB @16384.
// __launch_bounds__(512,2): 2 waves/EU minimum -> 256 VGPR cap, no spill (wreg 128 + acc 32 + xs 32 + stream 32).
__global__ __launch_bounds__(512, 2) void k_lstm_scan_mfma(const ushort16* __restrict__ xg,
                                                           const ushort16* __restrict__ w2,
                                                           ushort16* __restrict__ hout) {
    extern __shared__ char smem[];
    ushort16* hf = (ushort16*)smem;                 // 2 buffers x 4096 bf16
    ushort16* wl = (ushort16*)(smem + 16384);       // 65536 bf16 (kf 4,5)

    const int bg = blockIdx.x >> 1, d = blockIdx.x & 1;
    const int tid = threadIdx.x;
    const int wv = tid >> 6, lane = tid & 63;
    const int l15 = lane & 15, l4 = lane >> 4;
    const size_t dbase = (size_t)d * 262144;
    const int swl = (lane ^ (lane >> 3)) * 8;       // consumer chunk swizzle

    // zero h buffers
    for (int q = tid; q < 1024; q += 512) ((uint4*)hf)[q] = make_uint4(0, 0, 0, 0);
    // prefill LDS weights (kf 4,5 for all waves): 8192 uint4
    {
        const uint4* src = (const uint4*)(w2 + dbase);
        uint4* dst = (uint4*)wl;
        for (int q = tid; q < 8192; q += 512) {
            int s = q >> 7;              // w*8+nt
            int kp = (q >> 6) & 1;
            int off = q & 63;
            dst[q] = src[(s * 8 + 4 + kp) * 64 + off];
        }
    }
    // register weights kf 0..3 (128 VGPRs)
    const ushort16* wbase = w2 + dbase + (size_t)wv * 32768 + lane * 8;
    short8 wreg[8][4];
#pragma unroll
    for (int nt = 0; nt < 8; ++nt)
#pragma unroll
        for (int kf = 0; kf < 4; ++kf)
            wreg[nt][kf] = *(const short8*)&wbase[nt * 4096 + kf * 512];
    const ushort16* w6 = wbase + 6 * 512;   // kf6 base; kf7 = +512
    __syncthreads();

    float cst[2][4] = {{0.f, 0.f, 0.f, 0.f}, {0.f, 0.f, 0.f, 0.f}};
    int cur = 0;
    const ushort16* xgb = xg + (size_t)(bg * 16) * 1048576 + d * 1024 + wv * 32 + l15;

    for (int s = 0; s < 512; ++s) {
        const int tt = d ? (511 - s) : s;
        f32x4 acc[8] = {};
        const ushort16* hcur = hf + cur * 4096;

        // issue stream kf6 (opaque offset defeats loop-invariant hoisting)
        int off6 = 0;
        asm volatile("" : "+v"(off6));
        short8 w6r[8];
#pragma unroll
        for (int nt = 0; nt < 8; ++nt) w6r[nt] = *(const short8*)&w6[nt * 4096 + off6];

        // kf 0..3 from registers
#pragma unroll
        for (int kf = 0; kf < 4; ++kf) {
            short8 a = *(const short8*)&hcur[kf * 512 + swl];
#pragma unroll
            for (int nt = 0; nt < 8; ++nt)
                acc[nt] = __builtin_amdgcn_mfma_f32_16x16x32_bf16(a, wreg[nt][kf], acc[nt], 0, 0, 0);
        }

        // issue stream kf7
        int off7 = 0;
        asm volatile("" : "+v"(off7));
        short8 w7r[8];
#pragma unroll
        for (int nt = 0; nt < 8; ++nt) w7r[nt] = *(const short8*)&w6[nt * 4096 + 512 + off7];

        // xg loads (consumed in epilogue; latency hidden under remaining MFMAs)
        ushort16 xs[8][4];
        {
            const ushort16* xrow = xgb + (size_t)tt * 2048;
#pragma unroll
            for (int nt = 0; nt < 8; ++nt) {
                const int goff = (nt >> 1) * 256 + (nt & 1) * 16;
#pragma unroll
                for (int r = 0; r < 4; ++r)
                    xs[nt][r] = xrow[(size_t)(l4 * 4 + r) * 1048576 + goff];
            }
        }

        // kf6 (streamed)
        {
            short8 a = *(const short8*)&hcur[6 * 512 + swl];
#pragma unroll
            for (int nt = 0; nt < 8; ++nt)
                acc[nt] = __builtin_amdgcn_mfma_f32_16x16x32_bf16(a, w6r[nt], acc[nt], 0, 0, 0);
        }

        // kf 4,5 from LDS
#pragma unroll
        for (int kp = 0; kp < 2; ++kp) {
            short8 a = *(const short8*)&hcur[(4 + kp) * 512 + swl];
#pragma unroll
            for (int nt = 0; nt < 8; ++nt) {
                short8 b = *(const short8*)&wl[((wv * 8 + nt) * 2 + kp) * 512 + lane * 8];
                acc[nt] = __builtin_amdgcn_mfma_f32_16x16x32_bf16(a, b, acc[nt], 0, 0, 0);
            }
        }

        // kf7 (streamed)
        {
            short8 a = *(const short8*)&hcur[7 * 512 + swl];
#pragma unroll
            for (int nt = 0; nt < 8; ++nt)
                acc[nt] = __builtin_amdgcn_mfma_f32_16x16x32_bf16(a, w7r[nt], acc[nt], 0, 0, 0);
        }

        // epilogue: gates -> c,h ; write h to next A-fragment buffer (swizzled) + global
        ushort16* hnxt = hf + (cur ^ 1) * 4096;
#pragma unroll
        for (int hh = 0; hh < 2; ++hh) {
#pragma unroll
            for (int r = 0; r < 4; ++r) {
                float ip = acc[0 + hh][r] + bf2f(xs[0 + hh][r]);
                float fp = acc[2 + hh][r] + bf2f(xs[2 + hh][r]);
                float gp = acc[4 + hh][r] + bf2f(xs[4 + hh][r]);
                float op = acc[6 + hh][r] + bf2f(xs[6 + hh][r]);
                float ig = 1.f / (1.f + __expf(-ip));
                float fg = 1.f / (1.f + __expf(-fp));
                float gg = 1.f - 2.f / (__expf(2.f * gp) + 1.f);
                float og = 1.f / (1.f + __expf(-op));
                float c = fg * cst[hh][r] + ig * gg;
                cst[hh][r] = c;
                float h = og * (1.f - 2.f / (__expf(2.f * c) + 1.f));
                ushort16 hb = f2bf(h);
                int u = wv * 32 + hh * 16 + l15;
                int row = l4 * 4 + r;
                int lp = row + 16 * (hh * 2 + (l15 >> 3));
                int chunk = lp ^ (lp >> 3);        // producer swizzle (matches swl)
                hnxt[wv * 512 + chunk * 8 + (l15 & 7)] = hb;
                hout[((size_t)(bg * 16 + row) * 512 + tt) * 512 + d * 256 + u] = hb;
            }
        }
        __syncthreads();
        cur ^= 1;
    }
}

// ---------------- logits = h1[32768,512](bf16) @ clsW[9,512]^T + clsb -> f32 ----------------
__global__ __launch_bounds__(256) void k_logits(const ushort16* __restrict__ h1,
                                                const float* __restrict__ Wc,
                                                const float* __restrict__ bc,
                                                float* __restrict__ out) {
    __shared__ ushort16 hs[16 * 512];
    __shared__ float wsm[9 * 512];
    __shared__ float bs[9];
    const int tid = threadIdx.x;
    const size_t row0 = (size_t)blockIdx.x * 16;
    const uint4* src = (const uint4*)(h1 + row0 * 512);
    uint4* dst = (uint4*)hs;
#pragma unroll
    for (int i = 0; i < 4; i++) dst[tid + i * 256] = src[tid + i * 256];
    for (int i = tid; i < 4608; i += 256) wsm[i] = Wc[i];
    if (tid < 9) bs[tid] = bc[tid];
    __syncthreads();
    if (tid < 144) {
        int r = tid / 9, l = tid - r * 9;
        float acc = bs[l];
        const ushort16* hr = &hs[r * 512];
        const float* wrow = &wsm[l * 512];
        for (int k = 0; k < 512; k++) acc += bf2f(hr[k]) * wrow[k];
        out[(row0 + r) * 9 + l] = acc;
    }
}

// ---------------- CRF NLL per batch (timesteps [1, 511)) ----------------
__global__ __launch_bounds__(64) void k_crf(const float* __restrict__ logits,
                                            const int* __restrict__ labels,
                                            const float* __restrict__ start,
                                            const float* __restrict__ endv,
                                            const float* __restrict__ trans,
                                            float* __restrict__ perb) {
    const int b = blockIdx.x, lane = threadIdx.x;
    __shared__ float tr[81];
    __shared__ float emb[510 * 9];
    for (int i = lane; i < 81; i += 64) tr[i] = trans[i];
    const float* em = logits + (size_t)b * 512 * 9;
    for (int i = lane; i < 4590; i += 64) emb[i] = em[9 + i];
    __syncthreads();
    const int* lb = labels + (size_t)b * 512;

    float acc = 0.f;
    for (int s = lane; s < 510; s += 64) acc += emb[s * 9 + lb[s + 1]];
    for (int s = lane; s < 509; s += 64) acc += tr[lb[s + 1] * 9 + lb[s + 2]];
#pragma unroll
    for (int off = 32; off; off >>= 1) acc += __shfl_down(acc, off);

    const int j = (lane < 9) ? lane : 0;
    float alpha = start[j] + emb[j];
    for (int s = 1; s < 510; ++s) {
        float v[9];
        float m = -3.4e38f;
#pragma unroll
        for (int i = 0; i < 9; i++) {
            float ai = __shfl(alpha, i);
            float t = ai + tr[i * 9 + j];
            v[i] = t;
            m = fmaxf(m, t);
        }
        float sum = 0.f;
#pragma unroll
        for (int i = 0; i < 9; i++) sum += __expf(v[i] - m);
        alpha = m + __logf(sum) + emb[s * 9 + j];
    }
    float ae = alpha + endv[j];
    float mm = -3.4e38f;
#pragma unroll
    for (int i = 0; i < 9; i++) mm = fmaxf(mm, __shfl(ae, i));
    float ss = 0.f;
#pragma unroll
    for (int i = 0; i < 9; i++) ss += __expf(__shfl(ae, i) - mm);
    float logZ = mm + __logf(ss);
    if (lane == 0) {
        float num = acc + start[lb[1]] + endv[lb[510]];
        perb[b] = logZ - num;
    }
}

__global__ __launch_bounds__(64) void k_reduce(const float* __restrict__ perb,
                                               float* __restrict__ out) {
    float v = perb[threadIdx.x];
#pragma unroll
    for (int off = 32; off; off >>= 1) v += __shfl_down(v, off);
    if (threadIdx.x == 0) out[0] = v * (1.f / 64.f);
}

extern "C" void kernel_launch(void* const* d_in, const int* in_sizes, int n_in,
                              void* d_out, int out_size, void* d_ws, size_t ws_size,
                              hipStream_t stream) {
    const float* features = (const float*)d_in[0];
    const int*   labels   = (const int*)d_in[1];
    const float* w0ih = (const float*)d_in[3];
    const float* w0hh = (const float*)d_in[4];
    const float* b0   = (const float*)d_in[5];
    const float* w1ih = (const float*)d_in[6];
    const float* w1hh = (const float*)d_in[7];
    const float* b1   = (const float*)d_in[8];
    const float* clsW = (const float*)d_in[9];
    const float* clsb = (const float*)d_in[10];
    const float* cstart = (const float*)d_in[11];
    const float* cend   = (const float*)d_in[12];
    const float* ctrans = (const float*)d_in[13];

    char* ws = (char*)d_ws;
    ushort16* featbf = (ushort16*)(ws + 0);
    ushort16* h1buf  = (ushort16*)(ws + 0);
    ushort16* xg     = (ushort16*)(ws + 50331648);
    ushort16* h0     = (ushort16*)(ws + 184549376);
    ushort16* wih0   = (ushort16*)(ws + 218103808);
    ushort16* wih1   = (ushort16*)(ws + 221249536);
    ushort16* w2_0   = (ushort16*)(ws + 223346688);
    ushort16* w2_1   = (ushort16*)(ws + 224395264);
    float*    perb   = (float*)(ws + 225443840);

    float* outF = (float*)d_out;
    float* logitsF = outF + 1;

    k_cvt_bf16<<<dim3(2048), dim3(256), 0, stream>>>(features, featbf, 25165824 / 4);
    k_cvt_bf16<<<dim3(512), dim3(256), 0, stream>>>(w0ih, wih0, 1572864 / 4);
    k_cvt_bf16<<<dim3(512), dim3(256), 0, stream>>>(w1ih, wih1, 1048576 / 4);
    k_wfrag<<<dim3(2048), dim3(256), 0, stream>>>(w0hh, w2_0);
    k_wfrag<<<dim3(2048), dim3(256), 0, stream>>>(w1hh, w2_1);

    // layer 0
    k_gemm_bt<<<dim3(256, 16), dim3(256), 0, stream>>>(featbf, wih0, b0, xg, 32768, 2048, 768);
    k_lstm_scan_mfma<<<dim3(8), dim3(512), 147456, stream>>>(xg, w2_0, h0);
    // layer 1
    k_gemm_bt<<<dim3(256, 16), dim3(256), 0, stream>>>(h0, wih1, b1, xg, 32768, 2048, 512);
    k_lstm_scan_mfma<<<dim3(8), dim3(512), 147456, stream>>>(xg, w2_1, h1buf);
    // classifier + CRF
    k_logits<<<dim3(2048), dim3(256), 0, stream>>>(h1buf, clsW, clsb, logitsF);
    k_crf<<<dim3(64), dim3(64), 0, stream>>>(logitsF, labels, cstart, cend, ctrans, perb);
    k_reduce<<<dim3(1), dim3(64), 0, stream>>>(perb, outF);
}